// Round 3
// baseline (41271.811 us; speedup 1.0000x reference)
//
#include <hip/hip_runtime.h>

#define S_LEN 65536
#define HDIM 128

typedef _Float16 half2_t __attribute__((ext_vector_type(2)));
typedef _Float16 half8_t __attribute__((ext_vector_type(8)));
typedef float f32x4 __attribute__((ext_vector_type(4)));

__device__ __forceinline__ float sigm(float x) {
    return 1.0f / (1.0f + __expf(-x));
}
__device__ __forceinline__ float tanh_fast(float x) {
    return 2.0f / (1.0f + __expf(-2.0f * x)) - 1.0f;
}
__device__ __forceinline__ float dot2(half2_t a, half2_t b, float c) {
#if __has_builtin(__builtin_amdgcn_fdot2)
    return __builtin_amdgcn_fdot2(a, b, c, false);
#else
    return fmaf((float)a.x, (float)b.x, fmaf((float)a.y, (float)b.y, c));
#endif
}

// Raw workgroup barrier: drain LDS only (lgkmcnt), leave global loads/stores
// (x prefetch, h_hist) in flight across the barrier.
#define WG_BARRIER() do {                                         \
    asm volatile("s_waitcnt lgkmcnt(0)" ::: "memory");            \
    __builtin_amdgcn_s_barrier();                                 \
    asm volatile("" ::: "memory");                                \
} while (0)

// ================= Kernel 1: dot2 recurrence, 4 waves (1/SIMD) ============
// R9 post-mortem of R8: CU-local MfmaUtil 35% + VALUBusy 53% = pipes nearly
// saturated; MFMA pipe occupancy is ~500-620 cy/step because mfma_16x16x32
// computes 16 output columns and a matvec uses 1 (16x FLOP waste). That is
// a THROUGHPUT floor, not a scheduling artifact. Fix: v_dot2_f32_f16 on the
// VALU pipe -- 2 useful MACs/lane/instr, zero waste: 65536 MACs/step =
// 128 dot2/wave = ~256 cy/SIMD, half the MFMA pipe cost, and GSEL dies.
// Layout: wave w owns h[32w..32w+32). lane = (half=l>>5, j=l&31); each lane
// holds K-half [64*half,64*half+64) of all 4 gate rows of h[32w+j] in 128
// pinned VGPRs. Per step: 8 broadcast ds_read_b128 (own h-half, 2-way
// conflict = free), 128 dot2 in 8 chains (chunk-major: dots start as chunks
// land), K-halves combined by 4 shfl_xor(32). Both halves redundantly run
// the activation chain (uniform, no divergence); lanes<32 store h.
// Keeps: 1-barrier ping-pong h, x-prefetch depth 2, lgkm-only barrier.
__global__ __launch_bounds__(256)
__attribute__((amdgpu_waves_per_eu(1, 1)))
void lstm_seq_dot(const float* __restrict__ x,
                  const float* __restrict__ h0,
                  const float* __restrict__ c0,
                  const float* __restrict__ W_ih,
                  const float* __restrict__ W_hh,
                  const float* __restrict__ b_ih,
                  const float* __restrict__ b_hh,
                  _Float16* __restrict__ h_hist)
{
    __shared__ __align__(16) _Float16 h_buf[2][HDIM];  // ping-pong h_t (f16)

    const int tid  = threadIdx.x;       // 0..255, 4 waves
    const int lane = tid & 63;
    const int w    = tid >> 6;          // wave id 0..3: h-slice [32w,32w+32)
    const int j    = lane & 31;         // h element within slice
    const int half = lane >> 5;         // k-half: [64*half, 64*half+64)
    const int hidx = w * 32 + j;
    const int k0   = half * 64;

    // ---- W fragments: 4 gate rows x 8 chunks of 8 f16 = 128 VGPR ----
#define LOAD_WF(g, c) \
    half8_t wf_##g##_##c; { \
        const float* s_ = W_hh + (size_t)(hidx + 128 * (g)) * HDIM \
                               + k0 + 8 * (c); \
        wf_##g##_##c = (half8_t){ \
            (_Float16)s_[0], (_Float16)s_[1], (_Float16)s_[2], (_Float16)s_[3], \
            (_Float16)s_[4], (_Float16)s_[5], (_Float16)s_[6], (_Float16)s_[7] }; \
        asm volatile("" : "+v"(wf_##g##_##c)); }
    LOAD_WF(0,0) LOAD_WF(0,1) LOAD_WF(0,2) LOAD_WF(0,3)
    LOAD_WF(0,4) LOAD_WF(0,5) LOAD_WF(0,6) LOAD_WF(0,7)
    LOAD_WF(1,0) LOAD_WF(1,1) LOAD_WF(1,2) LOAD_WF(1,3)
    LOAD_WF(1,4) LOAD_WF(1,5) LOAD_WF(1,6) LOAD_WF(1,7)
    LOAD_WF(2,0) LOAD_WF(2,1) LOAD_WF(2,2) LOAD_WF(2,3)
    LOAD_WF(2,4) LOAD_WF(2,5) LOAD_WF(2,6) LOAD_WF(2,7)
    LOAD_WF(3,0) LOAD_WF(3,1) LOAD_WF(3,2) LOAD_WF(3,3)
    LOAD_WF(3,4) LOAD_WF(3,5) LOAD_WF(3,6) LOAD_WF(3,7)
#undef LOAD_WF

    // ---- Per-h-element state (replicated in both k-halves) ----
    const int r0 = hidx, r1 = hidx + 128, r2 = hidx + 256, r3 = hidx + 384;
    const float wi00 = W_ih[2 * r0], wi01 = W_ih[2 * r0 + 1];
    const float wi10 = W_ih[2 * r1], wi11 = W_ih[2 * r1 + 1];
    const float wi20 = W_ih[2 * r2], wi21 = W_ih[2 * r2 + 1];
    const float wi30 = W_ih[2 * r3], wi31 = W_ih[2 * r3 + 1];
    const float bs0 = b_ih[r0] + b_hh[r0];
    const float bs1 = b_ih[r1] + b_hh[r1];
    const float bs2 = b_ih[r2] + b_hh[r2];
    const float bs3 = b_ih[r3] + b_hh[r3];
    float c = c0[hidx];

    if (tid < HDIM) h_buf[0][tid] = (_Float16)h0[tid];
    __syncthreads();

    const float2* xp = (const float2*)x;
    float2 xcur = xp[0];                 // FIFO depth 2: covers L2 latency
    float2 xn1  = xp[1];

    // Per-lane h-half base pointers for the two ping-pong buffers.
    const half8_t* hb0 = ((const half8_t*)h_buf[0]) + 8 * half;
    const half8_t* hb1 = ((const half8_t*)h_buf[1]) + 8 * half;

    _Float16* hh = h_hist + hidx;        // store pointer (lanes<32 use it)

    // 4 f16 pairs of one chunk into one accumulator.
#define DOT8(acc, wv, hv) \
    acc = dot2((half2_t){wv[0], wv[1]}, (half2_t){hv[0], hv[1]}, acc); \
    acc = dot2((half2_t){wv[2], wv[3]}, (half2_t){hv[2], hv[3]}, acc); \
    acc = dot2((half2_t){wv[4], wv[5]}, (half2_t){hv[4], hv[5]}, acc); \
    acc = dot2((half2_t){wv[6], wv[7]}, (half2_t){hv[6], hv[7]}, acc);

    // One h-chunk against all 4 gates (chunk-major: consume in arrival order).
#define DCHUNK(a0_, a1_, a2_, a3_, c_, hv) \
    DOT8(a0_, wf_0_##c_, hv) \
    DOT8(a1_, wf_1_##c_, hv) \
    DOT8(a2_, wf_2_##c_, hv) \
    DOT8(a3_, wf_3_##c_, hv)

#define STEP(T, RB, WB, OFF) { \
    /* own h-half: 8 broadcast ds_read_b128 (2-way across halves = free) */ \
    half8_t hv0 = (RB)[0], hv1 = (RB)[1], hv2 = (RB)[2], hv3 = (RB)[3]; \
    half8_t hv4 = (RB)[4], hv5 = (RB)[5], hv6 = (RB)[6], hv7 = (RB)[7]; \
    int tn_ = (T) + 2; if (tn_ >= S_LEN) tn_ = S_LEN - 1; \
    float2 xnew_ = xp[tn_]; \
    /* xg fmas issue in the ds_read shadow */ \
    const float xg0 = fmaf(wi00, xcur.x, fmaf(wi01, xcur.y, bs0)); \
    const float xg1 = fmaf(wi10, xcur.x, fmaf(wi11, xcur.y, bs1)); \
    const float xg2 = fmaf(wi20, xcur.x, fmaf(wi21, xcur.y, bs2)); \
    const float xg3 = fmaf(wi30, xcur.x, fmaf(wi31, xcur.y, bs3)); \
    float sA0 = 0.f, sA1 = 0.f, sA2 = 0.f, sA3 = 0.f; \
    float sB0 = 0.f, sB1 = 0.f, sB2 = 0.f, sB3 = 0.f; \
    DCHUNK(sA0, sA1, sA2, sA3, 0, hv0) \
    DCHUNK(sB0, sB1, sB2, sB3, 1, hv1) \
    DCHUNK(sA0, sA1, sA2, sA3, 2, hv2) \
    DCHUNK(sB0, sB1, sB2, sB3, 3, hv3) \
    DCHUNK(sA0, sA1, sA2, sA3, 4, hv4) \
    DCHUNK(sB0, sB1, sB2, sB3, 5, hv5) \
    DCHUNK(sA0, sA1, sA2, sA3, 6, hv6) \
    DCHUNK(sB0, sB1, sB2, sB3, 7, hv7) \
    float s0 = sA0 + sB0; \
    float s1 = sA1 + sB1; \
    float s2 = sA2 + sB2; \
    float s3 = sA3 + sB3; \
    /* combine K-halves: both halves end with identical full sums */ \
    s0 += __shfl_xor(s0, 32, 64); \
    s1 += __shfl_xor(s1, 32, 64); \
    s2 += __shfl_xor(s2, 32, 64); \
    s3 += __shfl_xor(s3, 32, 64); \
    const float gi = sigm(s0 + xg0); \
    const float gf = sigm(s1 + xg1); \
    const float gg = tanh_fast(s2 + xg2); \
    const float go = sigm(s3 + xg3); \
    c = fmaf(gf, c, gi * gg); \
    const float hvx_ = go * tanh_fast(c); \
    const _Float16 hf_ = (_Float16)hvx_; \
    if (lane < 32) { \
        (WB)[hidx] = hf_;                 /* feeds next step's reads */ \
        hh[OFF] = hf_;                    /* h_hist, consumed by out_proj */ \
    } \
    xcur = xn1; xn1 = xnew_; \
    WG_BARRIER(); }

    #pragma unroll 1
    for (int t = 0; t < S_LEN; t += 2) {
        STEP(t,     hb0, h_buf[1], 0)
        STEP(t + 1, hb1, h_buf[0], HDIM)
        hh += 2 * HDIM;
    }
#undef STEP
#undef DCHUNK
#undef DOT8
}

// ================= Kernel 2: out[t] = tanh(h_t).W_out + b =================
__global__ __launch_bounds__(256)
void out_proj(const _Float16* __restrict__ h_hist,
              const float* __restrict__ W_out,
              const float* __restrict__ b_out,
              float* __restrict__ out)
{
    const int lane  = threadIdx.x & 63;
    const int gwave = (blockIdx.x * 256 + threadIdx.x) >> 6;
    const int nwave = (gridDim.x * 256) >> 6;

    const float wo0 = W_out[2 * lane + 0];
    const float wo1 = W_out[2 * lane + 1];
    const float bout = b_out[0];

    for (int t = gwave; t < S_LEN; t += nwave) {
        half2_t hv = ((const half2_t*)(h_hist + t * HDIM))[lane];
        float p = tanh_fast((float)hv.x) * wo0 + tanh_fast((float)hv.y) * wo1;
        #pragma unroll
        for (int off = 32; off > 0; off >>= 1)
            p += __shfl_xor(p, off, 64);
        if (lane == 0) out[t] = p + bout;
    }
}

// ================= Fallback: fused single kernel (ws too small) ===========
#define H_HI_OFF 144
__global__ __launch_bounds__(1024)
__attribute__((amdgpu_waves_per_eu(4, 4)))
void lstm_seq_full(const float* __restrict__ x,
                   const float* __restrict__ h0,
                   const float* __restrict__ c0,
                   const float* __restrict__ W_ih,
                   const float* __restrict__ W_hh,
                   const float* __restrict__ b_ih,
                   const float* __restrict__ b_hh,
                   const float* __restrict__ W_out,
                   const float* __restrict__ b_out,
                   float* __restrict__ out)
{
    __shared__ __align__(16) unsigned char h_raw[2 * H_HI_OFF];
    __shared__ float gates_part[2 * 512];
    __shared__ float red_sh[2];

    const int tid  = threadIdx.x;
    const int j    = tid >> 1;
    const int half = tid & 1;

    const float2* wr2 = (const float2*)(W_hh + j * HDIM + half * 64);
#define WDEF(i) half2_t W##i; { float2 t = wr2[i]; \
        W##i.x = (_Float16)t.x; W##i.y = (_Float16)t.y; } \
        asm volatile("" : "+v"(W##i));
    WDEF(0)  WDEF(1)  WDEF(2)  WDEF(3)  WDEF(4)  WDEF(5)  WDEF(6)  WDEF(7)
    WDEF(8)  WDEF(9)  WDEF(10) WDEF(11) WDEF(12) WDEF(13) WDEF(14) WDEF(15)
    WDEF(16) WDEF(17) WDEF(18) WDEF(19) WDEF(20) WDEF(21) WDEF(22) WDEF(23)
    WDEF(24) WDEF(25) WDEF(26) WDEF(27) WDEF(28) WDEF(29) WDEF(30) WDEF(31)
#undef WDEF

    float wih0 = 0.0f, wih1 = 0.0f, bias = 0.0f;
    if (half == 0) {
        wih0 = W_ih[2 * j + 0];
        wih1 = W_ih[2 * j + 1];
        bias = b_ih[j] + b_hh[j];
    }

    float c = 0.0f, wout = 0.0f;
    _Float16* hw = (_Float16*)(h_raw + ((tid < 64) ? 2 * tid
                                                   : H_HI_OFF + 2 * (tid - 64)));
    if (tid < HDIM) {
        c = c0[tid];
        wout = W_out[tid];
        *hw = (_Float16)h0[tid];
    }
    const float bout = b_out[0];
    __syncthreads();

    const float2* xp = (const float2*)x;
    float2 xcur = xp[0];
    const half8_t* hp = (const half8_t*)(h_raw + half * H_HI_OFF);

    #pragma unroll 1
    for (int t = 0; t < S_LEN; ++t) {
        const int tn = (t + 1 < S_LEN) ? (t + 1) : (S_LEN - 1);
        float2 xnext = xp[tn];

        float a0 = fmaf(wih0, xcur.x, fmaf(wih1, xcur.y, bias));
        float a1 = 0.0f, a2 = 0.0f, a3 = 0.0f;

#define CHUNK(cc, w0_, w1_, w2_, w3_) {                         \
        half8_t hv = hp[cc];                                    \
        half2_t p0 = { hv[0], hv[1] };                          \
        half2_t p1 = { hv[2], hv[3] };                          \
        half2_t p2 = { hv[4], hv[5] };                          \
        half2_t p3 = { hv[6], hv[7] };                          \
        a0 = dot2(w0_, p0, a0);                                 \
        a1 = dot2(w1_, p1, a1);                                 \
        a2 = dot2(w2_, p2, a2);                                 \
        a3 = dot2(w3_, p3, a3); }
        CHUNK(0, W0,  W1,  W2,  W3)
        CHUNK(1, W4,  W5,  W6,  W7)
        CHUNK(2, W8,  W9,  W10, W11)
        CHUNK(3, W12, W13, W14, W15)
        CHUNK(4, W16, W17, W18, W19)
        CHUNK(5, W20, W21, W22, W23)
        CHUNK(6, W24, W25, W26, W27)
        CHUNK(7, W28, W29, W30, W31)
#undef CHUNK

        gates_part[half * 512 + j] = (a0 + a1) + (a2 + a3);
        __syncthreads();

        if (tid < HDIM) {
            float gi = sigm(gates_part[tid]            + gates_part[tid + 512]);
            float gf = sigm(gates_part[tid + 128]      + gates_part[tid + 640]);
            float gg = tanh_fast(gates_part[tid + 256] + gates_part[tid + 768]);
            float go = sigm(gates_part[tid + 384]      + gates_part[tid + 896]);
            c = fmaf(gf, c, gi * gg);
            float h = go * tanh_fast(c);
            *hw = (_Float16)h;

            float p = tanh_fast(h) * wout;
            #pragma unroll
            for (int off = 32; off > 0; off >>= 1)
                p += __shfl_xor(p, off, 64);
            if ((tid & 63) == 0) red_sh[tid >> 6] = p;
        }
        __syncthreads();

        if (tid == 0) out[t] = red_sh[0] + red_sh[1] + bout;
        xcur = xnext;
    }
}

extern "C" void kernel_launch(void* const* d_in, const int* in_sizes, int n_in,
                              void* d_out, int out_size, void* d_ws, size_t ws_size,
                              hipStream_t stream) {
    const float* x     = (const float*)d_in[0];
    const float* h0    = (const float*)d_in[1];
    const float* c0    = (const float*)d_in[2];
    const float* W_ih  = (const float*)d_in[3];
    const float* W_hh  = (const float*)d_in[4];
    const float* b_ih  = (const float*)d_in[5];
    const float* b_hh  = (const float*)d_in[6];
    const float* W_out = (const float*)d_in[7];
    const float* b_out = (const float*)d_in[8];

    const size_t need = (size_t)S_LEN * HDIM * sizeof(_Float16);  // 16 MiB
    if (ws_size >= need) {
        _Float16* h_hist = (_Float16*)d_ws;
        lstm_seq_dot<<<dim3(1), dim3(256), 0, stream>>>(
            x, h0, c0, W_ih, W_hh, b_ih, b_hh, h_hist);
        out_proj<<<dim3(1024), dim3(256), 0, stream>>>(
            h_hist, W_out, b_out, (float*)d_out);
    } else {
        lstm_seq_full<<<dim3(1), dim3(1024), 0, stream>>>(
            x, h0, c0, W_ih, W_hh, b_ih, b_hh, W_out, b_out, (float*)d_out);
    }
}